// Round 1
// baseline (572.242 us; speedup 1.0000x reference)
//
#include <hip/hip_runtime.h>
#include <math.h>

#define NI 64
#define NO 64
#define NN 1024
#define NJ 960          // N - I: the "reg" region (global indices 64..1023)
#define NB 16384
#define NWARM 25

// ws layout, in floats:
//   S2c[j][m], j,m in [0,960): (d/N)*S[64+m][64+j]; rows m<64 are the masked
//             sources (global 64..127) and stored as 0.
//   Wt[j][k],  j in [0,960), k in [0,64): (d/N)*S[k][64+j]
//   hd[j]   : head contribution during warmup = (1/N) * sum_k Wt[j][k]
//   base[j] : r25[j] + (d/N)*sum_m r25[m]*S2[m][j]  (batch-step constant)
//   ybuf[2][960] : ping-pong unnormalized warmup state
//   slots[32]    : s_t normalization sums (slot[0]=1)
#define OFF_S2   0u
#define OFF_WT   (960u * 960u)            // 921600
#define OFF_HD   (OFF_WT + 960u * 64u)    // 983040
#define OFF_BASE (OFF_HD + 960u)          // 984000
#define OFF_YB   (OFF_BASE + 960u)        // 984960
#define OFF_SLOT (OFF_YB + 2u * 960u)     // 986880  (total ~3.95 MB)

__global__ void init_k(float* __restrict__ ws) {
  int t = threadIdx.x;
  if (t < NJ) ws[OFF_YB + t] = 1.0f / (float)NN;   // y_0 = conc0 tail
  if (t == NJ) ws[OFF_SLOT] = 1.0f;                // s_0 = 1 (y_0 already normalized)
  int s = t - (NJ + 1);
  if (s >= 0 && s < 31) ws[OFF_SLOT + 1 + s] = 0.0f;
}

__global__ void prep_k(const float* __restrict__ ident,
                       const float* __restrict__ enh,
                       const float* __restrict__ inh,
                       const float* __restrict__ beta,
                       const float* __restrict__ delta,
                       float* __restrict__ ws) {
  const int j = blockIdx.x;            // 0..959 -> global column 64+j
  const float b = beta[0];
  const float dN = delta[0] / (float)NN;
  const float cj = ident[64 + j];

  // S2c row j: sources are global rows 64+m; rows with m<64 are masked -> 0
  for (int m = threadIdx.x; m < NJ; m += blockDim.x) {
    float v = 0.0f;
    if (m >= 64) {
      int g = 64 + m;
      v = dN * (expf(-b * fabsf(enh[g] - cj)) - expf(-b * fabsf(inh[g] - cj)));
    }
    ws[OFF_S2 + (size_t)j * NJ + m] = v;
  }
  // Wt row j (head sources k<64, unmasked) + hd[j]
  float wv = 0.0f;
  if (threadIdx.x < 64) {
    int k = threadIdx.x;
    wv = dN * (expf(-b * fabsf(enh[k] - cj)) - expf(-b * fabsf(inh[k] - cj)));
    ws[OFF_WT + (size_t)j * 64 + k] = wv;
    float h = wv;
    #pragma unroll
    for (int off = 32; off >= 1; off >>= 1) h += __shfl_xor(h, off);
    if (k == 0) ws[OFF_HD + j] = h / (float)NN;
  }
}

// One warmup iteration t (or, FINAL: compute base[] from the converged state).
// Reads y_t (unnormalized) and s_t = slots[t]; writes y_{t+1} and accumulates
// s_{t+1} into slots[t+1] (one atomicAdd per block).
template <bool FINAL>
__global__ void warm_k(float* __restrict__ ws, int t) {
  const int grp = threadIdx.x >> 6;    // 4 column-groups of 64 lanes
  const int l = threadIdx.x & 63;
  const int j = blockIdx.x * 4 + grp;
  const float* __restrict__ S2row = ws + OFF_S2 + (size_t)j * NJ;
  const float* __restrict__ ycur = ws + OFF_YB + (size_t)(t & 1) * NJ;
  float* __restrict__ ynext = ws + OFF_YB + (size_t)((t + 1) & 1) * NJ;

  float dot = 0.0f;
  #pragma unroll
  for (int i = 0; i < 15; ++i) {       // 960 / 64
    int m = l + i * 64;
    dot = fmaf(ycur[m], S2row[m], dot);
  }
  #pragma unroll
  for (int off = 32; off >= 1; off >>= 1) dot += __shfl_xor(dot, off);

  __shared__ float blocksum;
  if (threadIdx.x == 0) blocksum = 0.0f;
  __syncthreads();

  if (l == 0) {
    float s = ws[OFF_SLOT + t];
    float pre = ycur[j] + dot;                 // (y_t[j] + y_t . S2col_j)
    pre = (s > 0.0f) ? pre / s : pre;          // = r_t[j] + tail part of dc_j
    if (!FINAL) {
      float yv = fmaxf(pre + ws[OFF_HD + j], 0.0f);
      ynext[j] = yv;
      atomicAdd(&blocksum, yv);
    } else {
      ws[OFF_BASE + j] = pre;                  // head comes from inputs later
    }
  }
  __syncthreads();
  if (!FINAL && threadIdx.x == 0) atomicAdd(&ws[OFF_SLOT + t + 1], blocksum);
}

__device__ __forceinline__ float dot16(const float* __restrict__ a,
                                       const float4* __restrict__ w) {
  float4 w0 = w[0], w1 = w[1], w2 = w[2], w3 = w[3];
  float s0 = fmaf(a[3], w0.w, fmaf(a[2], w0.z, fmaf(a[1], w0.y, a[0] * w0.x)));
  float s1 = fmaf(a[7], w1.w, fmaf(a[6], w1.z, fmaf(a[5], w1.y, a[4] * w1.x)));
  float s2 = fmaf(a[11], w2.w, fmaf(a[10], w2.z, fmaf(a[9], w2.y, a[8] * w2.x)));
  float s3 = fmaf(a[15], w3.w, fmaf(a[14], w3.z, fmaf(a[13], w3.y, a[12] * w3.x)));
  return (s0 + s1) + (s2 + s3);
}

// 4 lanes per row; lane c holds inputs k in [16c, 16c+16). Per column j:
// 16 FMAs + xor-butterfly over the 4 lanes -> full pre-activation.
__global__ __launch_bounds__(256) void batch_k(const float* __restrict__ inp,
                                               const float* __restrict__ ws,
                                               float* __restrict__ out) {
  const int c = threadIdx.x & 3;
  const int r = blockIdx.x * 64 + (threadIdx.x >> 2);
  const float* __restrict__ Wt = ws + OFF_WT;
  const float* __restrict__ base = ws + OFF_BASE;

  float a[16];
  {
    const float4* ip = (const float4*)(inp + (size_t)r * 64 + c * 16);
    float4 v0 = ip[0], v1 = ip[1], v2 = ip[2], v3 = ip[3];
    a[0] = v0.x; a[1] = v0.y; a[2] = v0.z; a[3] = v0.w;
    a[4] = v1.x; a[5] = v1.y; a[6] = v1.z; a[7] = v1.w;
    a[8] = v2.x; a[9] = v2.y; a[10] = v2.z; a[11] = v2.w;
    a[12] = v3.x; a[13] = v3.y; a[14] = v3.z; a[15] = v3.w;
  }

  float y[16];
  float ssum = 0.0f;

  // j < 64: these are the output columns -> stash y. Full unroll so the y[]
  // index is a compile-time constant (no scratch spill).
  #pragma unroll
  for (int j = 0; j < 64; ++j) {
    float d4 = dot16(a, (const float4*)(Wt + (size_t)j * 64 + c * 16));
    d4 += __shfl_xor(d4, 1);
    d4 += __shfl_xor(d4, 2);
    float yv = fmaxf(d4 + base[j], 0.0f);
    ssum += yv;
    if ((j >> 4) == c) y[j & 15] = yv;
  }
  // j >= 64: only contribute to the normalization sum.
  #pragma unroll 4
  for (int j = 64; j < NJ; ++j) {
    float d4 = dot16(a, (const float4*)(Wt + (size_t)j * 64 + c * 16));
    d4 += __shfl_xor(d4, 1);
    d4 += __shfl_xor(d4, 2);
    ssum += fmaxf(d4 + base[j], 0.0f);
  }

  float invs = (ssum > 0.0f) ? 1.0f / ssum : 1.0f;
  float4* op = (float4*)(out + (size_t)r * 64 + c * 16);
  float4 o;
  o.x = y[0] * invs;  o.y = y[1] * invs;  o.z = y[2] * invs;  o.w = y[3] * invs;  op[0] = o;
  o.x = y[4] * invs;  o.y = y[5] * invs;  o.z = y[6] * invs;  o.w = y[7] * invs;  op[1] = o;
  o.x = y[8] * invs;  o.y = y[9] * invs;  o.z = y[10] * invs; o.w = y[11] * invs; op[2] = o;
  o.x = y[12] * invs; o.y = y[13] * invs; o.z = y[14] * invs; o.w = y[15] * invs; op[3] = o;
}

extern "C" void kernel_launch(void* const* d_in, const int* in_sizes, int n_in,
                              void* d_out, int out_size, void* d_ws, size_t ws_size,
                              hipStream_t stream) {
  const float* inp   = (const float*)d_in[0];
  const float* ident = (const float*)d_in[1];
  const float* enh   = (const float*)d_in[2];
  const float* inh   = (const float*)d_in[3];
  const float* beta  = (const float*)d_in[4];
  const float* delta = (const float*)d_in[5];
  float* ws  = (float*)d_ws;
  float* out = (float*)d_out;

  hipLaunchKernelGGL(init_k, dim3(1), dim3(1024), 0, stream, ws);
  hipLaunchKernelGGL(prep_k, dim3(960), dim3(256), 0, stream,
                     ident, enh, inh, beta, delta, ws);
  for (int t = 0; t < NWARM; ++t)
    hipLaunchKernelGGL((warm_k<false>), dim3(240), dim3(256), 0, stream, ws, t);
  hipLaunchKernelGGL((warm_k<true>), dim3(240), dim3(256), 0, stream, ws, NWARM);
  hipLaunchKernelGGL(batch_k, dim3(256), dim3(256), 0, stream, inp, ws, out);
}